// Round 1
// baseline (341.789 us; speedup 1.0000x reference)
//
#include <hip/hip_runtime.h>

#define BLOCK       256
#define UNROLL      4
#define MAX_BLOCKS  4096

// Per-point GICP mahalanobis: maha = res^T * adj(RCR) * res / det(RCR)
// RCR = C_tar[idx] + T3 * C_src * T3^T  (3x3 symmetric SPD)
__device__ __forceinline__ float gicp_point(
    int i,
    const float t00, const float t01, const float t02,
    const float t10, const float t11, const float t12,
    const float t20, const float t21, const float t22,
    const float t30, const float t31, const float t32,
    const float4* __restrict__ src, const float4* __restrict__ tar,
    const float4* __restrict__ cs,  const float4* __restrict__ ct,
    const int*    __restrict__ idx)
{
    // idx first: it heads the dependent gather chain
    const int    j  = idx[i];
    const float4 s  = src[i];
    const float4 tp = tar[j];

    const size_t bj = (size_t)j * 4;
    const float4 d0 = ct[bj + 0];
    const float4 d1 = ct[bj + 1];
    const float4 d2 = ct[bj + 2];

    const size_t bi = (size_t)i * 4;
    const float4 c0 = cs[bi + 0];
    const float4 c1 = cs[bi + 1];
    const float4 c2 = cs[bi + 2];

    const float ts0 = s.x * t00 + s.y * t10 + s.z * t20 + s.w * t30;
    const float ts1 = s.x * t01 + s.y * t11 + s.z * t21 + s.w * t31;
    const float ts2 = s.x * t02 + s.y * t12 + s.z * t22 + s.w * t32;
    const float r0 = tp.x - ts0;
    const float r1 = tp.y - ts1;
    const float r2 = tp.z - ts2;

    // U = T3 * C
    const float u00 = t00*c0.x + t01*c1.x + t02*c2.x;
    const float u01 = t00*c0.y + t01*c1.y + t02*c2.y;
    const float u02 = t00*c0.z + t01*c1.z + t02*c2.z;
    const float u10 = t10*c0.x + t11*c1.x + t12*c2.x;
    const float u11 = t10*c0.y + t11*c1.y + t12*c2.y;
    const float u12 = t10*c0.z + t11*c1.z + t12*c2.z;
    const float u20 = t20*c0.x + t21*c1.x + t22*c2.x;
    const float u21 = t20*c0.y + t21*c1.y + t22*c2.y;
    const float u22 = t20*c0.z + t21*c1.z + t22*c2.z;

    // tcov = U * T3^T (symmetric part only)
    const float tc00 = u00*t00 + u01*t01 + u02*t02;
    const float tc01 = u00*t10 + u01*t11 + u02*t12;
    const float tc02 = u00*t20 + u01*t21 + u02*t22;
    const float tc11 = u10*t10 + u11*t11 + u12*t12;
    const float tc12 = u10*t20 + u11*t21 + u12*t22;
    const float tc22 = u20*t20 + u21*t21 + u22*t22;

    const float a = d0.x + tc00;
    const float b = d0.y + tc01;
    const float c = d0.z + tc02;
    const float d = d1.y + tc11;
    const float e = d1.z + tc12;
    const float f = d2.z + tc22;

    const float A00 = d * f - e * e;
    const float A01 = c * e - b * f;
    const float A02 = b * e - c * d;
    const float A11 = a * f - c * c;
    const float A12 = b * c - a * e;
    const float A22 = a * d - b * b;

    const float det = a * A00 + b * A01 + c * A02;

    const float num = r0 * r0 * A00 + r1 * r1 * A11 + r2 * r2 * A22
                    + 2.0f * (r0 * r1 * A01 + r0 * r2 * A02 + r1 * r2 * A12);

    return num / det;
}

__global__ __launch_bounds__(BLOCK) void gicp_maha_kernel(
    const float*  __restrict__ T,
    const float4* __restrict__ src,
    const float4* __restrict__ tar,
    const float4* __restrict__ cs,
    const float4* __restrict__ ct,
    const int*    __restrict__ idx,
    float*        __restrict__ partial,  // [gridDim.x], each written once
    int n)
{
    const float t00 = T[0],  t01 = T[1],  t02 = T[2];
    const float t10 = T[4],  t11 = T[5],  t12 = T[6];
    const float t20 = T[8],  t21 = T[9],  t22 = T[10];
    const float t30 = T[12], t31 = T[13], t32 = T[14];

    const int stride = gridDim.x * BLOCK;      // grid exactly tiles n/UNROLL
    const int step   = stride * UNROLL;

    float local = 0.0f;
    // With grid = ceil(n/(BLOCK*UNROLL)) this outer loop runs exactly once
    // per thread; EVERY point goes through the 4-independent-chain body.
    for (int base = blockIdx.x * BLOCK + threadIdx.x; base < n; base += step) {
        if (base + 3 * stride < n) {
            // fast path (all but the last ~896 threads): unconditional,
            // 4 idx->gather chains issued back-to-back, full MLP
            float v0 = gicp_point(base,            t00,t01,t02,t10,t11,t12,t20,t21,t22,t30,t31,t32, src,tar,cs,ct,idx);
            float v1 = gicp_point(base +   stride, t00,t01,t02,t10,t11,t12,t20,t21,t22,t30,t31,t32, src,tar,cs,ct,idx);
            float v2 = gicp_point(base + 2*stride, t00,t01,t02,t10,t11,t12,t20,t21,t22,t30,t31,t32, src,tar,cs,ct,idx);
            float v3 = gicp_point(base + 3*stride, t00,t01,t02,t10,t11,t12,t20,t21,t22,t30,t31,t32, src,tar,cs,ct,idx);
            local += (v0 + v1) + (v2 + v3);
        } else {
            // boundary: clamp index + zero-mask so the 4 chains remain
            // unconditional (no exec-mask serialization of the MLP)
            #pragma unroll
            for (int k = 0; k < UNROLL; ++k) {
                int i = base + k * stride;
                const float m = (i < n) ? 1.0f : 0.0f;
                i = (i < n) ? i : (n - 1);
                local += m * gicp_point(i, t00,t01,t02,t10,t11,t12,t20,t21,t22,t30,t31,t32, src,tar,cs,ct,idx);
            }
        }
    }

    // wave-64 reduction
    for (int off = 32; off > 0; off >>= 1)
        local += __shfl_down(local, off, 64);

    __shared__ float wsum[BLOCK / 64];
    const int wave = threadIdx.x >> 6;
    if ((threadIdx.x & 63) == 0) wsum[wave] = local;
    __syncthreads();
    if (threadIdx.x == 0) {
        float s = wsum[0];
        #pragma unroll
        for (int w = 1; w < BLOCK / 64; ++w) s += wsum[w];
        partial[blockIdx.x] = s;   // contention-free: one store per block
    }
}

__global__ __launch_bounds__(256) void gicp_finalize_kernel(
    const float* __restrict__ partial, float* __restrict__ out,
    double scale, int nblocks)
{
    double s = 0.0;
    for (int k = threadIdx.x; k < nblocks; k += 256)
        s += (double)partial[k];
    for (int off = 32; off > 0; off >>= 1)
        s += __shfl_down(s, off, 64);
    __shared__ double wsum[4];
    const int wave = threadIdx.x >> 6;
    if ((threadIdx.x & 63) == 0) wsum[wave] = s;
    __syncthreads();
    if (threadIdx.x == 0)
        out[0] = (float)((wsum[0] + wsum[1] + wsum[2] + wsum[3]) * scale);
}

extern "C" void kernel_launch(void* const* d_in, const int* in_sizes, int n_in,
                              void* d_out, int out_size, void* d_ws, size_t ws_size,
                              hipStream_t stream) {
    const float*  T   = (const float*)d_in[0];
    const float4* src = (const float4*)d_in[1];
    const float4* tar = (const float4*)d_in[2];
    const float4* cs  = (const float4*)d_in[3];
    const float4* ct  = (const float4*)d_in[4];
    const int*    idx = (const int*)d_in[5];
    const int n = in_sizes[1] / 4;  // src_points is (N,4) -> in_sizes in floats... (N*4 floats)/4

    // Exact tiling: every thread gets exactly UNROLL points through the
    // 4-chain body; no serial remainder loop anywhere.
    int nblocks = (n + BLOCK * UNROLL - 1) / (BLOCK * UNROLL);
    if (nblocks < 1) nblocks = 1;
    if (nblocks > MAX_BLOCKS) nblocks = MAX_BLOCKS;
    const int ws_cap = (int)(ws_size / sizeof(float));
    if (nblocks > ws_cap) nblocks = ws_cap;

    float* partial = (float*)d_ws;  // nblocks floats, fully overwritten

    gicp_maha_kernel<<<nblocks, BLOCK, 0, stream>>>(T, src, tar, cs, ct,
                                                    idx, partial, n);
    gicp_finalize_kernel<<<1, 256, 0, stream>>>(partial, (float*)d_out,
                                                0.5 / (double)n, nblocks);
}

// Round 2
// 334.144 us; speedup vs baseline: 1.0229x; 1.0229x over previous
//
#include <hip/hip_runtime.h>
#include <stdint.h>

#define BLOCK       256
#define WPB         (BLOCK / 64)
#define MAX_BLOCKS  4096

// global_load_lds: writes 16B per lane to wave-uniform LDS base + lane*16.
typedef __attribute__((address_space(3))) uint32_t       lds_u32;
typedef __attribute__((address_space(1))) const uint32_t glb_u32;

__device__ __forceinline__ void coop_load16(const void* gptr, void* lds_uniform_base) {
    __builtin_amdgcn_global_load_lds((glb_u32*)gptr, (lds_u32*)lds_uniform_base, 16, 0, 0);
}

__global__ __launch_bounds__(BLOCK) void gicp_maha_kernel(
    const float*  __restrict__ T,
    const float4* __restrict__ src,
    const float4* __restrict__ tar,
    const float4* __restrict__ cs,
    const float4* __restrict__ ct,
    const int*    __restrict__ idx,
    float*        __restrict__ partial,
    int n, int nbatches)
{
    // [wave][cs|ct][64 points * 4 rows of float4] = 4KB per region, 32KB/block
    __shared__ float4 stage[WPB][2][256];

    const int lane   = threadIdx.x & 63;
    const int wv     = threadIdx.x >> 6;
    const int gwave  = blockIdx.x * WPB + wv;
    const int nwaves = gridDim.x * WPB;

    const float t00 = T[0],  t01 = T[1],  t02 = T[2];
    const float t10 = T[4],  t11 = T[5],  t12 = T[6];
    const float t20 = T[8],  t21 = T[9],  t22 = T[10];
    const float t30 = T[12], t31 = T[13], t32 = T[14];

    float4* const st_cs = &stage[wv][0][0];
    float4* const st_ct = &stage[wv][1][0];

    float local = 0.0f;

    // grid-stride over 64-point batches; one point per lane per batch.
    for (int b = gwave; b < nbatches; b += nwaves) {
        const int base = b * 64;
        int i = base + lane;
        const float msk = (i < n) ? 1.0f : 0.0f;
        i = (i < n) ? i : (n - 1);

        const int    j  = idx[i];     // heads the gather chain
        const float4 s  = src[i];     // coalesced
        const float4 tp = tar[j];     // divergent, 1 line/pt (optimal)

        // --- cooperative cs stage: pure linear, 16 pts (64B blocks) per instr ---
        const char* const cs_bytes = (const char*)cs;
        #pragma unroll
        for (int g = 0; g < 4; ++g) {
            int q = base + g * 16 + (lane >> 2);          // point this lane serves
            q = (q < n) ? q : (n - 1);
            const void* gp = cs_bytes + (size_t)q * 64 + (size_t)(lane & 3) * 16;
            coop_load16(gp, (char*)st_cs + g * 1024);
        }

        // --- cooperative ct stage: 4 lanes fetch the 4 rows of one point's block ---
        // TA merges the 4 same-line lanes -> 16 line-requests/instr instead of 64.
        const char* const ct_bytes = (const char*)ct;
        #pragma unroll
        for (int g = 0; g < 4; ++g) {
            const int jg = __shfl(j, (lane >> 2) + g * 16, 64);
            const void* gp = ct_bytes + (size_t)jg * 64 + (size_t)(lane & 3) * 16;
            coop_load16(gp, (char*)st_ct + g * 1024);
        }

        // all staging is intra-wave: vmcnt drain only, no barrier needed
        asm volatile("s_waitcnt vmcnt(0)" ::: "memory");
        __builtin_amdgcn_sched_barrier(0);

        // each lane reads its own point back (64B stride ds_read_b128, ~baseline cost)
        const float4 c0 = st_cs[lane * 4 + 0];
        const float4 c1 = st_cs[lane * 4 + 1];
        const float4 c2 = st_cs[lane * 4 + 2];
        const float4 d0 = st_ct[lane * 4 + 0];
        const float4 d1 = st_ct[lane * 4 + 1];
        const float4 d2 = st_ct[lane * 4 + 2];

        // transformed src + residual
        const float ts0 = s.x * t00 + s.y * t10 + s.z * t20 + s.w * t30;
        const float ts1 = s.x * t01 + s.y * t11 + s.z * t21 + s.w * t31;
        const float ts2 = s.x * t02 + s.y * t12 + s.z * t22 + s.w * t32;
        const float r0 = tp.x - ts0;
        const float r1 = tp.y - ts1;
        const float r2 = tp.z - ts2;

        // U = T3 * C_src
        const float u00 = t00*c0.x + t01*c1.x + t02*c2.x;
        const float u01 = t00*c0.y + t01*c1.y + t02*c2.y;
        const float u02 = t00*c0.z + t01*c1.z + t02*c2.z;
        const float u10 = t10*c0.x + t11*c1.x + t12*c2.x;
        const float u11 = t10*c0.y + t11*c1.y + t12*c2.y;
        const float u12 = t10*c0.z + t11*c1.z + t12*c2.z;
        const float u20 = t20*c0.x + t21*c1.x + t22*c2.x;
        const float u21 = t20*c0.y + t21*c1.y + t22*c2.y;
        const float u22 = t20*c0.z + t21*c1.z + t22*c2.z;

        // tcov = U * T3^T (symmetric part)
        const float tc00 = u00*t00 + u01*t01 + u02*t02;
        const float tc01 = u00*t10 + u01*t11 + u02*t12;
        const float tc02 = u00*t20 + u01*t21 + u02*t22;
        const float tc11 = u10*t10 + u11*t11 + u12*t12;
        const float tc12 = u10*t20 + u11*t21 + u12*t22;
        const float tc22 = u20*t20 + u21*t21 + u22*t22;

        const float a = d0.x + tc00;
        const float bb = d0.y + tc01;
        const float c = d0.z + tc02;
        const float d = d1.y + tc11;
        const float e = d1.z + tc12;
        const float f = d2.z + tc22;

        const float A00 = d * f - e * e;
        const float A01 = c * e - bb * f;
        const float A02 = bb * e - c * d;
        const float A11 = a * f - c * c;
        const float A12 = bb * c - a * e;
        const float A22 = a * d - bb * bb;

        const float det = a * A00 + bb * A01 + c * A02;

        const float num = r0 * r0 * A00 + r1 * r1 * A11 + r2 * r2 * A22
                        + 2.0f * (r0 * r1 * A01 + r0 * r2 * A02 + r1 * r2 * A12);

        local += msk * (num / det);
    }

    // wave-64 reduction
    for (int off = 32; off > 0; off >>= 1)
        local += __shfl_down(local, off, 64);

    __shared__ float wsum[WPB];
    if ((threadIdx.x & 63) == 0) wsum[wv] = local;
    __syncthreads();
    if (threadIdx.x == 0) {
        float ssum = wsum[0];
        #pragma unroll
        for (int w = 1; w < WPB; ++w) ssum += wsum[w];
        partial[blockIdx.x] = ssum;
    }
}

__global__ __launch_bounds__(256) void gicp_finalize_kernel(
    const float* __restrict__ partial, float* __restrict__ out,
    double scale, int nblocks)
{
    double s = 0.0;
    for (int k = threadIdx.x; k < nblocks; k += 256)
        s += (double)partial[k];
    for (int off = 32; off > 0; off >>= 1)
        s += __shfl_down(s, off, 64);
    __shared__ double wsum[4];
    const int wave = threadIdx.x >> 6;
    if ((threadIdx.x & 63) == 0) wsum[wave] = s;
    __syncthreads();
    if (threadIdx.x == 0)
        out[0] = (float)((wsum[0] + wsum[1] + wsum[2] + wsum[3]) * scale);
}

extern "C" void kernel_launch(void* const* d_in, const int* in_sizes, int n_in,
                              void* d_out, int out_size, void* d_ws, size_t ws_size,
                              hipStream_t stream) {
    const float*  T   = (const float*)d_in[0];
    const float4* src = (const float4*)d_in[1];
    const float4* tar = (const float4*)d_in[2];
    const float4* cs  = (const float4*)d_in[3];
    const float4* ct  = (const float4*)d_in[4];
    const int*    idx = (const int*)d_in[5];
    const int n = in_sizes[1] / 4;  // src_points is (N,4)

    const int nbatches = (n + 63) / 64;
    // ~4 batches per wave
    int nblocks = (nbatches + WPB * 4 - 1) / (WPB * 4);
    if (nblocks < 1) nblocks = 1;
    if (nblocks > MAX_BLOCKS) nblocks = MAX_BLOCKS;
    const int ws_cap = (int)(ws_size / sizeof(float));
    if (nblocks > ws_cap) nblocks = ws_cap;

    float* partial = (float*)d_ws;

    gicp_maha_kernel<<<nblocks, BLOCK, 0, stream>>>(T, src, tar, cs, ct, idx,
                                                    partial, n, nbatches);
    gicp_finalize_kernel<<<1, 256, 0, stream>>>(partial, (float*)d_out,
                                                0.5 / (double)n, nblocks);
}